// Round 2
// baseline (236.508 us; speedup 1.0000x reference)
//
#include <hip/hip_runtime.h>

#define HW    512
#define OUTW  128
#define NIMG  96                          // 32*3
#define N_HR  ((long long)NIMG*HW*HW)     // 25165824
#define N_LR  ((long long)NIMG*OUTW*OUTW) // 1572864
#define NPART (NIMG*64)                   // one slot per wave (2 out rows each)

// PyTorch bicubic kernel, a = -0.75
__device__ __forceinline__ float cubic075(float x){
    float ax = fabsf(x);
    float ax2 = ax*ax, ax3 = ax2*ax;
    const float A = -0.75f;
    float f1 = (A+2.f)*ax3 - (A+3.f)*ax2 + 1.f;
    float f2 = A*ax3 - 5.f*A*ax2 + 8.f*A*ax - 4.f*A;
    return ax <= 1.f ? f1 : (ax < 2.f ? f2 : 0.f);
}

// scale=4 antialiased window: 16 taps, dist=(k-7.5)/4, normalized.
// Shift-invariant across all output positions (verified absmax=0.0).
__device__ __forceinline__ void get_weights(float w[16]){
    float s = 0.f;
#pragma unroll
    for (int k = 0; k < 16; ++k){
        float d = ((float)k - 7.5f) * 0.25f;
        w[k] = cubic075(d);
        s += w[k];
    }
#pragma unroll
    for (int k = 0; k < 16; ++k) w[k] /= s;
}

// Fully fused, barrier-free. One WAVE = (img, 2 consecutive output rows).
// R2: same structure as the proven R0 kernel (depth-2 rotating prefetch with
// RUNTIME-GUARDED issues -- the guards are what keep the ring buffers
// register-resident; R1's branch-free restructure let the compiler sink all
// loads next to their consumers, VGPR 76->36, pipeline collapsed, -11%).
// Only change vs R0: 2 output rows per wave instead of 4 -> 20-row window,
// grid NIMG*16 = 1536 blocks = 6 waves/SIMD (was 3). We are latency-bound
// (VALUBusy 9-14%, HBM 19%), so TLP is the lever.
__global__ __launch_bounds__(256) void kmain(const float* __restrict__ pred,
                                             const float* __restrict__ tgt,
                                             const float* __restrict__ lr,
                                             double* __restrict__ part){
    const int img = blockIdx.x >> 4;
    const int tid = threadIdx.x;
    const int w   = tid >> 6;                 // wave in block 0..3
    const int l   = tid & 63;
    const int gw  = ((blockIdx.x & 15) << 2) + w;  // wave in image 0..63
    const int o0  = gw << 1;                  // first output row (2 per wave)
    const int s   = (gw << 3) - 6;            // first (unclamped) input row

    float wt[16]; get_weights(wt);
    const float* P = pred + (size_t)img * (HW*HW);
    const float* T = tgt  + (size_t)img * (HW*HW);
    const float* L = lr   + (size_t)img * (OUTW*OUTW);

    float acc[2][2] = {{0.f,0.f},{0.f,0.f}};
    float pix_acc = 0.f, lr_acc = 0.f;

    // depth-2 rotating prefetch: (c)=row i, (n)=row i+1, issue row i+2 ->(f)
    int r0 = min(HW-1, max(0, s + 0));
    int r1 = min(HW-1, max(0, s + 1));
    const float4* rp0 = (const float4*)(P + (size_t)r0 * HW);
    const float4* rp1 = (const float4*)(P + (size_t)r1 * HW);
    float4 c0 = rp0[2*l], c1 = rp0[2*l+1];
    float4 n0 = rp1[2*l], n1 = rp1[2*l+1];
    float4 tc0, tc1, tn0, tn1;   // tgt pipeline (valid when window reached)

#pragma unroll 4
    for (int i = 0; i < 20; ++i){
        // issue prefetches for row i+2
        float4 f0, f1, tf0, tf1;
        if (i < 18){
            int rn = min(HW-1, max(0, s + i + 2));
            const float4* rp = (const float4*)(P + (size_t)rn * HW);
            f0 = rp[2*l]; f1 = rp[2*l+1];
        }
        if (i + 2 >= 6 && i + 2 < 14){
            const float4* tp = (const float4*)(T + (size_t)(s + i + 2) * HW);
            tf0 = tp[2*l]; tf1 = tp[2*l+1];
        }

        const float p0=c0.x,p1v=c0.y,p2v=c0.z,p3=c0.w,
                    p4=c1.x,p5=c1.y,p6=c1.z,p7=c1.w;

        // pix term: wave owns input rows s+6..s+13
        if (i >= 6 && i < 14){
            pix_acc += fabsf(p0-tc0.x)+fabsf(p1v-tc0.y)+fabsf(p2v-tc0.z)+fabsf(p3-tc0.w)
                     + fabsf(p4-tc1.x)+fabsf(p5-tc1.y)+fabsf(p6-tc1.z)+fabsf(p7-tc1.w);
        }

        // horizontal halo via shuffles: cols 8l-6..8l-1 and 8l+8..8l+13
        float Lm6 = __shfl_up(p2v,1,64), Lm5 = __shfl_up(p3,1,64),
              Lm4 = __shfl_up(p4,1,64),  Lm3 = __shfl_up(p5,1,64),
              Lm2 = __shfl_up(p6,1,64),  Lm1 = __shfl_up(p7,1,64);
        float R8  = __shfl_down(p0,1,64), R9  = __shfl_down(p1v,1,64),
              R10 = __shfl_down(p2v,1,64),R11 = __shfl_down(p3,1,64),
              R12 = __shfl_down(p4,1,64), R13 = __shfl_down(p5,1,64);
        if (l == 0){ Lm6=p0; Lm5=p0; Lm4=p0; Lm3=p0; Lm2=p0; Lm1=p0; }
        if (l == 63){ R8=p7; R9=p7; R10=p7; R11=p7; R12=p7; R13=p7; }

        float w20[20] = {Lm6,Lm5,Lm4,Lm3,Lm2,Lm1,p0,p1v,p2v,p3,p4,p5,p6,p7,
                         R8,R9,R10,R11,R12,R13};
        float h0 = 0.f, h1 = 0.f;
#pragma unroll
        for (int k = 0; k < 16; ++k){
            h0 += wt[k]*w20[k];
            h1 += wt[k]*w20[k+4];
        }

        // vertical accumulate into the 2 output rows this wave owns
#pragma unroll
        for (int q = 0; q < 2; ++q){
            int k = i - 4*q;
            if (k >= 0 && k < 16){
                acc[q][0] += wt[k]*h0;
                acc[q][1] += wt[k]*h1;
            }
        }

        // rotate pipelines
        c0=n0; c1=n1; n0=f0; n1=f1;
        tc0=tn0; tc1=tn1; tn0=tf0; tn1=tf1;
    }

    // lr term: lane l holds out cols 2l,2l+1 for rows o0..o0+1
#pragma unroll
    for (int q = 0; q < 2; ++q){
        const float2 lv = *(const float2*)(L + (size_t)(o0+q)*OUTW + 2*l);
        lr_acc += fabsf(acc[q][0]-lv.x) + fabsf(acc[q][1]-lv.y);
    }

    // intra-wave reduction, one slot per wave (no atomics, no init needed)
#pragma unroll
    for (int off = 32; off > 0; off >>= 1){
        pix_acc += __shfl_down(pix_acc, off, 64);
        lr_acc  += __shfl_down(lr_acc,  off, 64);
    }
    if (l == 0){
        const int slot = (blockIdx.x << 2) + w;
        part[slot]         = (double)pix_acc;
        part[NPART + slot] = (double)lr_acc;
    }
}

__global__ __launch_bounds__(256) void k3(const double* __restrict__ part,
                                          float* __restrict__ out){
    const int t = threadIdx.x;
    double v1 = 0.0, v2 = 0.0;
    for (int i = t; i < NPART; i += 256){
        v1 += part[i];
        v2 += part[NPART + i];
    }
#pragma unroll
    for (int off = 32; off > 0; off >>= 1){
        v1 += __shfl_down(v1, off, 64);
        v2 += __shfl_down(v2, off, 64);
    }
    __shared__ double s1[4], s2[4];
    const int lane = t & 63, wid = t >> 6;
    if (lane == 0){ s1[wid] = v1; s2[wid] = v2; }
    __syncthreads();
    if (t == 0){
        double S1 = s1[0]+s1[1]+s1[2]+s1[3];
        double S2 = s2[0]+s2[1]+s2[2]+s2[3];
        float pix     = (float)(S1 / (double)N_HR);
        float lr_term = (float)(S2 / (double)N_LR);
        float pair    = 0.f;
        float consist = 1.0f * lr_term + 1.0f * pair;   // LAM_LR, LAM_PAIR
        float total   = pix + 0.1f * consist;           // LAM_CONSIST
        out[0] = total; out[1] = pix; out[2] = consist; out[3] = lr_term; out[4] = pair;
    }
}

extern "C" void kernel_launch(void* const* d_in, const int* in_sizes, int n_in,
                              void* d_out, int out_size, void* d_ws, size_t ws_size,
                              hipStream_t stream){
    const float* pred = (const float*)d_in[0];
    const float* tgt  = (const float*)d_in[1];
    const float* lrr  = (const float*)d_in[2];
    float* out = (float*)d_out;

    double* part = (double*)d_ws;   // 2 * 6144 doubles = 96 KB, every slot written

    kmain<<<NIMG*16, 256, 0, stream>>>(pred, tgt, lrr, part);
    k3<<<1, 256, 0, stream>>>(part, out);
}